// Round 5
// baseline (174.015 us; speedup 1.0000x reference)
//
#include <hip/hip_runtime.h>

// VectorQuantizer R4: input (16,64,64,64) f32 channel-first, codebook (1024,64) f32.
// out = [quantized (16,64,64,64) f32 | indices (16,64,64) as f32].
//
// A = codebook (-2*c baked, + esq-as-f16-split 5th k-chunk), B = tokens, via
// mfma_f32_32x32x16_f16 -> acc[r] == score. Packed-slot top-2 tracking
// (3 VALU/score), near-ties (gap < EPS) get exact fp32 full-K rescan.
// R4 deltas vs R3 (structure only, numerics identical):
//  - block = 64 tokens, 4 waves = 4 K-quarters; grid 1024 (4 blocks/CU,
//    4 waves/SIMD; R3 had 2).
//  - cooperative B staging: block loads 64x64 input tile coalesced ONCE into
//    fragment-ordered LDS; waves ds_read_b128 their fragments.
//  - explicit prefetch pipeline on A-fragment stream (next tile loads under
//    current tile's MFMA+tracking).

typedef _Float16 v8h  __attribute__((ext_vector_type(8)));
typedef float    v16f __attribute__((ext_vector_type(16)));

constexpr int   D         = 64;
constexpr int   K         = 1024;
constexpr int   HW        = 4096;
constexpr int   DHW       = D * HW;
constexpr int   OUT_ELEMS = 16 * DHW;
constexpr float EPS       = 0.065f;

// CH: 32 tiles x 5 chunks (4 data + 1 esq) x 64 lanes x 8 f16 = 160 KB.
// frag f = t*5+kc; CH[f*512 + lane*8 + j]:
//   kc<4 : A[row = t*32 + (lane&31)][k = kc*16 + (lane>>5)*8 + j] = -2*c
//   kc==4: lh==0: j0=e_hi, j1=e_lo, else 0 (pairs with B5 = ones at k=0,1)

__global__ __launch_bounds__(256) void vq_prep(
    const float* __restrict__ cb, _Float16* __restrict__ CH, float* __restrict__ esq)
{
    const int blk = blockIdx.x, tid = threadIdx.x;
    if (blk < 40) {
        const int gid  = blk * 256 + tid;          // [0, 10240)
        const int lane = gid & 63;
        const int fid  = gid >> 6;                 // [0, 160)
        const int t    = fid / 5;
        const int kc   = fid - 5 * t;
        const int l31  = lane & 31;
        const int lh   = lane >> 5;
        const int cw   = t * 32 + l31;
        v8h h;
        if (kc < 4) {
            const float* src = cb + cw * D + kc * 16 + lh * 8;
            #pragma unroll
            for (int j = 0; j < 8; ++j) h[j] = (_Float16)(-2.0f * src[j]);
        } else {
            #pragma unroll
            for (int j = 0; j < 8; ++j) h[j] = (_Float16)0.0f;
            if (lh == 0) {
                const float4* c4 = (const float4*)(cb + cw * D);
                float a0 = 0.f, a1 = 0.f, a2 = 0.f, a3 = 0.f;
                #pragma unroll
                for (int j = 0; j < 16; ++j) {
                    const float4 c = c4[j];
                    a0 = fmaf(c.x, c.x, a0);
                    a1 = fmaf(c.y, c.y, a1);
                    a2 = fmaf(c.z, c.z, a2);
                    a3 = fmaf(c.w, c.w, a3);
                }
                const float e   = (a0 + a1) + (a2 + a3);
                const _Float16 ehi = (_Float16)e;
                h[0] = ehi;
                h[1] = (_Float16)(e - (float)ehi);
            }
        }
        *(v8h*)(CH + (size_t)fid * 512 + lane * 8) = h;
    } else {
        const int cw = (blk - 40) * 256 + tid;     // exact f32 e_sq for rescan
        const float4* c4 = (const float4*)(cb + cw * D);
        float a0 = 0.f, a1 = 0.f, a2 = 0.f, a3 = 0.f;
        #pragma unroll
        for (int j = 0; j < 16; ++j) {
            const float4 c = c4[j];
            a0 = fmaf(c.x, c.x, a0);
            a1 = fmaf(c.y, c.y, a1);
            a2 = fmaf(c.z, c.z, a2);
            a3 = fmaf(c.w, c.w, a3);
        }
        esq[cw] = (a0 + a1) + (a2 + a3);
    }
}

__global__ __launch_bounds__(256, 4) void vq_scan(
    const float* __restrict__ input,
    const float* __restrict__ codebook,
    const _Float16* __restrict__ CH,
    const float* __restrict__ esq,
    float* __restrict__ out)
{
    __shared__ _Float16 s_bf[2][4][64][8];   // B fragments, 8 KB, shared by all waves
    __shared__ float    s_pv[4][64];         // per-quarter best (packed)
    __shared__ float    s_p2[4][64];         // per-quarter second best
    __shared__ int      s_pk[4][64];         // per-quarter best cw
    __shared__ int      s_idx[64];
    __shared__ unsigned s_mask[2];
    __shared__ float    s_x[4][64];          // rescan x staging per wave

    const int tid  = threadIdx.x;
    const int lane = tid & 63;
    const int q    = __builtin_amdgcn_readfirstlane(tid >> 6);  // K-quarter
    const int l31  = lane & 31;
    const int lh   = lane >> 5;
    const int tok0 = blockIdx.x * 64;
    const int b    = tok0 >> 12;
    const int hwb  = tok0 & 4095;

    if (tid < 2) s_mask[tid] = 0u;

    // ---- cooperative B staging: 64 tokens x 64 channels, coalesced, ONCE ----
    // element (d, tk) -> s_bf[tk>>5][d>>4][((d>>3)&1)*32 + (tk&31)][d&7]
    {
        const float* xb = input + (size_t)b * DHW + hwb;
        const int tk = tid & 63;
        const int dh = tid >> 6;             // 0..3
        #pragma unroll
        for (int rep = 0; rep < 16; ++rep) {
            const int d = rep * 4 + dh;
            const float v = xb[(size_t)d * HW + tk];
            s_bf[tk >> 5][d >> 4][((d >> 3) & 1) * 32 + (tk & 31)][d & 7] = (_Float16)v;
        }
    }
    __syncthreads();

    // ---- B fragments from LDS: 2 col-tiles x 4 k-chunks (ds_read_b128) ----
    v8h bt[2][4];
    #pragma unroll
    for (int ct = 0; ct < 2; ++ct)
        #pragma unroll
        for (int kc = 0; kc < 4; ++kc)
            bt[ct][kc] = *(const v8h*)&s_bf[ct][kc][lane][0];

    // B5: ones at k=0,1 (pairs with esq chunk)
    v8h b5;
    #pragma unroll
    for (int j = 0; j < 8; ++j) b5[j] = (_Float16)0.0f;
    if (lh == 0) { b5[0] = (_Float16)1.0f; b5[1] = (_Float16)1.0f; }

    v16f Z = {0,0,0,0,0,0,0,0,0,0,0,0,0,0,0,0};
    const float INF = __builtin_huge_valf();
    float bv0 = INF, b20 = INF, bv1 = INF, b21 = INF;

    const v8h* Abase = (const v8h*)CH + lane;

    // ---- hot loop: 8 tiles, software-pipelined A-frag loads ----
    v8h a0, a1, a2, a3, a5;
    {
        const v8h* Ap = Abase + (size_t)((q * 8 + 0) * 5) * 64;
        a0 = Ap[0]; a1 = Ap[64]; a2 = Ap[128]; a3 = Ap[192]; a5 = Ap[256];
    }
    #pragma unroll 2
    for (int t = 0; t < 8; ++t) {
        const int tn = (t < 7) ? t + 1 : 7;
        const v8h* Apn = Abase + (size_t)((q * 8 + tn) * 5) * 64;
        v8h n0 = Apn[0], n1 = Apn[64], n2 = Apn[128], n3 = Apn[192], n5 = Apn[256];

        v16f acc0 = __builtin_amdgcn_mfma_f32_32x32x16_f16(a5, b5, Z, 0, 0, 0);
        v16f acc1 = __builtin_amdgcn_mfma_f32_32x32x16_f16(a5, b5, Z, 0, 0, 0);
        acc0 = __builtin_amdgcn_mfma_f32_32x32x16_f16(a0, bt[0][0], acc0, 0, 0, 0);
        acc1 = __builtin_amdgcn_mfma_f32_32x32x16_f16(a0, bt[1][0], acc1, 0, 0, 0);
        acc0 = __builtin_amdgcn_mfma_f32_32x32x16_f16(a1, bt[0][1], acc0, 0, 0, 0);
        acc1 = __builtin_amdgcn_mfma_f32_32x32x16_f16(a1, bt[1][1], acc1, 0, 0, 0);
        acc0 = __builtin_amdgcn_mfma_f32_32x32x16_f16(a2, bt[0][2], acc0, 0, 0, 0);
        acc1 = __builtin_amdgcn_mfma_f32_32x32x16_f16(a2, bt[1][2], acc1, 0, 0, 0);
        acc0 = __builtin_amdgcn_mfma_f32_32x32x16_f16(a3, bt[0][3], acc0, 0, 0, 0);
        acc1 = __builtin_amdgcn_mfma_f32_32x32x16_f16(a3, bt[1][3], acc1, 0, 0, 0);

        // acc[r] IS the score. Pack slot into low 8 mantissa bits, track top-2.
        #pragma unroll
        for (int r = 0; r < 16; ++r) {
            const unsigned slot = (unsigned)((t << 4) | r);
            const float s0 = __uint_as_float((__float_as_uint(acc0[r]) & 0xFFFFFF00u) | slot);
            b20 = __builtin_amdgcn_fmed3f(s0, bv0, b20);
            bv0 = fminf(bv0, s0);
            const float s1 = __uint_as_float((__float_as_uint(acc1[r]) & 0xFFFFFF00u) | slot);
            b21 = __builtin_amdgcn_fmed3f(s1, bv1, b21);
            bv1 = fminf(bv1, s1);
        }
        a0 = n0; a1 = n1; a2 = n2; a3 = n3; a5 = n5;
    }

    // ---- cross-half-row merge (lane <-> lane^32), decode cw, stash to LDS ----
    #pragma unroll
    for (int ct = 0; ct < 2; ++ct) {
        const float bv = ct ? bv1 : bv0;
        const float b2 = ct ? b21 : b20;
        const float obv = __shfl_xor(bv, 32, 64);
        const float ob2 = __shfl_xor(b2, 32, 64);
        const float B1 = fminf(bv, obv);
        const float B2 = fminf(fmaxf(bv, obv), fminf(b2, ob2));
        const int   lho = (obv < bv) ? (lh ^ 1) : lh;   // tie keeps own (lanes<32: lh=0)
        const unsigned slot = __float_as_uint(B1) & 255u;
        const int r  = slot & 15;
        const int tt = slot >> 4;
        const int cw = (q * 8 + tt) * 32 + (r & 3) + 8 * (r >> 2) + 4 * lho;
        if (lane < 32) {
            s_pv[q][ct * 32 + lane] = B1;
            s_p2[q][ct * 32 + lane] = B2;
            s_pk[q][ct * 32 + lane] = cw;
        }
    }
    __syncthreads();

    // ---- merge 4 quarters per token (ascending q, strict < => first-index) ----
    if (tid < 64) {
        float B1 = INF, B2 = INF; int CW = 0;
        #pragma unroll
        for (int qq = 0; qq < 4; ++qq) {
            const float pv = s_pv[qq][tid];
            const float p2 = s_p2[qq][tid];
            const int   pk = s_pk[qq][tid];
            if (pv < B1) { B2 = fminf(B1, p2); B1 = pv; CW = pk; }
            else         { B2 = fminf(B2, pv); }
        }
        s_idx[tid] = CW;
        if (B2 - B1 < EPS) atomicOr(&s_mask[tid >> 5], 1u << (tid & 31));
    }
    __syncthreads();

    // ---- exact fp32 rescan for uncertain tokens (rare), wave-parallel ----
    {
        int ui = 0;
        for (int w = 0; w < 2; ++w) {
            unsigned m = s_mask[w];
            while (m) {
                const int bit = __ffs(m) - 1;
                m &= m - 1;
                const int tl = w * 32 + bit;
                if ((ui & 3) == q) {
                    const int hw = hwb + tl;
                    s_x[q][lane] = input[(size_t)b * DHW + (size_t)lane * HW + hw];
                    const float4* xs4 = (const float4*)s_x[q];
                    float bestv = INF; int bestk = K;
                    for (int rr = 0; rr < 16; ++rr) {
                        const int k = lane + rr * 64;
                        const float4* c4 = (const float4*)(codebook + (size_t)k * D);
                        float a0s = 0.f, a1s = 0.f, a2s = 0.f, a3s = 0.f;
                        #pragma unroll
                        for (int j = 0; j < 16; ++j) {
                            const float4 c  = c4[j];
                            const float4 xv = xs4[j];
                            a0s = fmaf(xv.x, c.x, a0s);
                            a1s = fmaf(xv.y, c.y, a1s);
                            a2s = fmaf(xv.z, c.z, a2s);
                            a3s = fmaf(xv.w, c.w, a3s);
                        }
                        const float s = fmaf(-2.0f, (a0s + a1s) + (a2s + a3s), esq[k]);
                        if (s < bestv) { bestv = s; bestk = k; }   // ascending k
                    }
                    #pragma unroll
                    for (int off = 32; off >= 1; off >>= 1) {
                        const float ov = __shfl_xor(bestv, off, 64);
                        const int   ok = __shfl_xor(bestk, off, 64);
                        if (ov < bestv || (ov == bestv && ok < bestk)) { bestv = ov; bestk = ok; }
                    }
                    if (lane == 0) s_idx[tl] = bestk;
                }
                ++ui;
            }
        }
    }
    __syncthreads();

    // ---- epilogue: gather codebook row, coalesced per-channel stores ----
    {
        const int tkn = tid & 63;
        const int dq  = tid >> 6;                 // 0..3: channels [dq*16, dq*16+16)
        const int idx = s_idx[tkn];
        const int hw  = hwb + tkn;
        const float4* c4 = (const float4*)(codebook + (size_t)idx * D + dq * 16);
        float* op = out + (size_t)b * DHW + (size_t)dq * 16 * HW + hw;
        #pragma unroll
        for (int j = 0; j < 4; ++j) {
            const float4 c = c4[j];
            op[(size_t)(4 * j + 0) * HW] = c.x;
            op[(size_t)(4 * j + 1) * HW] = c.y;
            op[(size_t)(4 * j + 2) * HW] = c.z;
            op[(size_t)(4 * j + 3) * HW] = c.w;
        }
        if (tid < 64) out[OUT_ELEMS + tok0 + tid] = (float)s_idx[tid];
    }
}

extern "C" void kernel_launch(void* const* d_in, const int* in_sizes, int n_in,
                              void* d_out, int out_size, void* d_ws, size_t ws_size,
                              hipStream_t stream) {
    const float* input    = (const float*)d_in[0];
    const float* codebook = (const float*)d_in[1];
    float* out            = (float*)d_out;

    _Float16* CH  = (_Float16*)d_ws;                   // 163840 B
    float*    esq = (float*)((char*)d_ws + 163840);    // 4096 B

    vq_prep<<<44, 256, 0, stream>>>(codebook, CH, esq);
    vq_scan<<<1024, 256, 0, stream>>>(input, codebook, CH, esq, out);
}

// Round 6
// 129.486 us; speedup vs baseline: 1.3439x; 1.3439x over previous
//
#include <hip/hip_runtime.h>

// VectorQuantizer R5: input (16,64,64,64) f32 channel-first, codebook (1024,64) f32.
// out = [quantized (16,64,64,64) f32 | indices (16,64,64) as f32].
//
// A = codebook (-2*c baked, + esq-as-f16-split 5th k-chunk), B = tokens, via
// mfma_f32_32x32x16_f16 -> acc[r] == score. Packed-slot top-2 tracking,
// near-ties (gap < EPS) get exact fp32 full-K rescan.
// R5 deltas vs R4 (numerics of scan path identical):
//  - COALESCED rescan: lane=(row,quarter), contiguous codebook reads, quad
//    shfl-reduce, esq from LDS. ~8x cheaper/token -> kills straggler tail.
//  - staging loads float4-vectorized (4 VMEM/thread vs 16).
//  - epilogue: winner rows gathered to LDS once, stores float4 (4 vs 16).

typedef _Float16 v8h  __attribute__((ext_vector_type(8)));
typedef float    v16f __attribute__((ext_vector_type(16)));

constexpr int   D         = 64;
constexpr int   K         = 1024;
constexpr int   HW        = 4096;
constexpr int   DHW       = D * HW;
constexpr int   OUT_ELEMS = 16 * DHW;
constexpr float EPS       = 0.065f;

// CH: 32 tiles x 5 chunks (4 data + 1 esq) x 64 lanes x 8 f16 = 160 KB.
// frag f = t*5+kc; CH[f*512 + lane*8 + j]:
//   kc<4 : A[row = t*32 + (lane&31)][k = kc*16 + (lane>>5)*8 + j] = -2*c
//   kc==4: lh==0: j0=e_hi, j1=e_lo, else 0 (pairs with B5 = ones at k=0,1)

__global__ __launch_bounds__(256) void vq_prep(
    const float* __restrict__ cb, _Float16* __restrict__ CH, float* __restrict__ esq)
{
    const int blk = blockIdx.x, tid = threadIdx.x;
    if (blk < 40) {
        const int gid  = blk * 256 + tid;          // [0, 10240)
        const int lane = gid & 63;
        const int fid  = gid >> 6;                 // [0, 160)
        const int t    = fid / 5;
        const int kc   = fid - 5 * t;
        const int l31  = lane & 31;
        const int lh   = lane >> 5;
        const int cw   = t * 32 + l31;
        v8h h;
        if (kc < 4) {
            const float* src = cb + cw * D + kc * 16 + lh * 8;
            #pragma unroll
            for (int j = 0; j < 8; ++j) h[j] = (_Float16)(-2.0f * src[j]);
        } else {
            #pragma unroll
            for (int j = 0; j < 8; ++j) h[j] = (_Float16)0.0f;
            if (lh == 0) {
                const float4* c4 = (const float4*)(cb + cw * D);
                float a0 = 0.f, a1 = 0.f, a2 = 0.f, a3 = 0.f;
                #pragma unroll
                for (int j = 0; j < 16; ++j) {
                    const float4 c = c4[j];
                    a0 = fmaf(c.x, c.x, a0);
                    a1 = fmaf(c.y, c.y, a1);
                    a2 = fmaf(c.z, c.z, a2);
                    a3 = fmaf(c.w, c.w, a3);
                }
                const float e   = (a0 + a1) + (a2 + a3);
                const _Float16 ehi = (_Float16)e;
                h[0] = ehi;
                h[1] = (_Float16)(e - (float)ehi);
            }
        }
        *(v8h*)(CH + (size_t)fid * 512 + lane * 8) = h;
    } else {
        const int cw = (blk - 40) * 256 + tid;     // exact f32 e_sq for rescan
        const float4* c4 = (const float4*)(cb + cw * D);
        float a0 = 0.f, a1 = 0.f, a2 = 0.f, a3 = 0.f;
        #pragma unroll
        for (int j = 0; j < 16; ++j) {
            const float4 c = c4[j];
            a0 = fmaf(c.x, c.x, a0);
            a1 = fmaf(c.y, c.y, a1);
            a2 = fmaf(c.z, c.z, a2);
            a3 = fmaf(c.w, c.w, a3);
        }
        esq[cw] = (a0 + a1) + (a2 + a3);
    }
}

__global__ __launch_bounds__(256, 4) void vq_scan(
    const float* __restrict__ input,
    const float* __restrict__ codebook,
    const _Float16* __restrict__ CH,
    const float* __restrict__ esq,
    float* __restrict__ out)
{
    __shared__ _Float16 s_bf[2][4][64][8];   // B fragments, 8 KB
    __shared__ float    s_esq[K];            // exact e_sq, 4 KB (for rescan)
    __shared__ float    s_pv[4][64];
    __shared__ float    s_p2[4][64];
    __shared__ int      s_pk[4][64];
    __shared__ int      s_idx[64];
    __shared__ unsigned s_mask[2];
    __shared__ float    s_x[4][64];          // rescan x staging per wave
    __shared__ float    s_q[64][65];         // winner rows for epilogue, 16.6 KB

    const int tid  = threadIdx.x;
    const int lane = tid & 63;
    const int q    = __builtin_amdgcn_readfirstlane(tid >> 6);  // K-quarter
    const int l31  = lane & 31;
    const int lh   = lane >> 5;
    const int tok0 = blockIdx.x * 64;
    const int b    = tok0 >> 12;
    const int hwb  = tok0 & 4095;

    if (tid < 2) s_mask[tid] = 0u;

    // ---- stage exact e_sq into LDS (1 float4/thread) ----
    *(float4*)&s_esq[tid * 4] = *(const float4*)&esq[tid * 4];

    // ---- cooperative B staging: 4 float4 loads/thread, same dest mapping as R4 ----
    {
        const float* xb = input + (size_t)b * DHW + hwb;
        #pragma unroll
        for (int pass = 0; pass < 4; ++pass) {
            const int d   = pass * 16 + (tid >> 4);
            const int hw4 = (tid & 15) * 4;
            const float4 v = *(const float4*)(xb + (size_t)d * HW + hw4);
            const float vv[4] = {v.x, v.y, v.z, v.w};
            #pragma unroll
            for (int u = 0; u < 4; ++u) {
                const int tk = hw4 + u;
                s_bf[tk >> 5][d >> 4][((d >> 3) & 1) * 32 + (tk & 31)][d & 7] = (_Float16)vv[u];
            }
        }
    }
    __syncthreads();

    // ---- B fragments from LDS ----
    v8h bt[2][4];
    #pragma unroll
    for (int ct = 0; ct < 2; ++ct)
        #pragma unroll
        for (int kc = 0; kc < 4; ++kc)
            bt[ct][kc] = *(const v8h*)&s_bf[ct][kc][lane][0];

    // B5: ones at k=0,1 (pairs with esq chunk)
    v8h b5;
    #pragma unroll
    for (int j = 0; j < 8; ++j) b5[j] = (_Float16)0.0f;
    if (lh == 0) { b5[0] = (_Float16)1.0f; b5[1] = (_Float16)1.0f; }

    v16f Z = {0,0,0,0,0,0,0,0,0,0,0,0,0,0,0,0};
    const float INF = __builtin_huge_valf();
    float bv0 = INF, b20 = INF, bv1 = INF, b21 = INF;

    const v8h* Abase = (const v8h*)CH + lane;

    // ---- hot loop: 8 tiles ----
    v8h a0, a1, a2, a3, a5;
    {
        const v8h* Ap = Abase + (size_t)((q * 8 + 0) * 5) * 64;
        a0 = Ap[0]; a1 = Ap[64]; a2 = Ap[128]; a3 = Ap[192]; a5 = Ap[256];
    }
    #pragma unroll 2
    for (int t = 0; t < 8; ++t) {
        const int tn = (t < 7) ? t + 1 : 7;
        const v8h* Apn = Abase + (size_t)((q * 8 + tn) * 5) * 64;
        v8h n0 = Apn[0], n1 = Apn[64], n2 = Apn[128], n3 = Apn[192], n5 = Apn[256];

        v16f acc0 = __builtin_amdgcn_mfma_f32_32x32x16_f16(a5, b5, Z, 0, 0, 0);
        v16f acc1 = __builtin_amdgcn_mfma_f32_32x32x16_f16(a5, b5, Z, 0, 0, 0);
        acc0 = __builtin_amdgcn_mfma_f32_32x32x16_f16(a0, bt[0][0], acc0, 0, 0, 0);
        acc1 = __builtin_amdgcn_mfma_f32_32x32x16_f16(a0, bt[1][0], acc1, 0, 0, 0);
        acc0 = __builtin_amdgcn_mfma_f32_32x32x16_f16(a1, bt[0][1], acc0, 0, 0, 0);
        acc1 = __builtin_amdgcn_mfma_f32_32x32x16_f16(a1, bt[1][1], acc1, 0, 0, 0);
        acc0 = __builtin_amdgcn_mfma_f32_32x32x16_f16(a2, bt[0][2], acc0, 0, 0, 0);
        acc1 = __builtin_amdgcn_mfma_f32_32x32x16_f16(a2, bt[1][2], acc1, 0, 0, 0);
        acc0 = __builtin_amdgcn_mfma_f32_32x32x16_f16(a3, bt[0][3], acc0, 0, 0, 0);
        acc1 = __builtin_amdgcn_mfma_f32_32x32x16_f16(a3, bt[1][3], acc1, 0, 0, 0);

        #pragma unroll
        for (int r = 0; r < 16; ++r) {
            const unsigned slot = (unsigned)((t << 4) | r);
            const float s0 = __uint_as_float((__float_as_uint(acc0[r]) & 0xFFFFFF00u) | slot);
            b20 = __builtin_amdgcn_fmed3f(s0, bv0, b20);
            bv0 = fminf(bv0, s0);
            const float s1 = __uint_as_float((__float_as_uint(acc1[r]) & 0xFFFFFF00u) | slot);
            b21 = __builtin_amdgcn_fmed3f(s1, bv1, b21);
            bv1 = fminf(bv1, s1);
        }
        a0 = n0; a1 = n1; a2 = n2; a3 = n3; a5 = n5;
    }

    // ---- cross-half-row merge (lane <-> lane^32), decode cw ----
    #pragma unroll
    for (int ct = 0; ct < 2; ++ct) {
        const float bv = ct ? bv1 : bv0;
        const float b2 = ct ? b21 : b20;
        const float obv = __shfl_xor(bv, 32, 64);
        const float ob2 = __shfl_xor(b2, 32, 64);
        const float B1 = fminf(bv, obv);
        const float B2 = fminf(fmaxf(bv, obv), fminf(b2, ob2));
        const int   lho = (obv < bv) ? (lh ^ 1) : lh;
        const unsigned slot = __float_as_uint(B1) & 255u;
        const int r  = slot & 15;
        const int tt = slot >> 4;
        const int cw = (q * 8 + tt) * 32 + (r & 3) + 8 * (r >> 2) + 4 * lho;
        if (lane < 32) {
            s_pv[q][ct * 32 + lane] = B1;
            s_p2[q][ct * 32 + lane] = B2;
            s_pk[q][ct * 32 + lane] = cw;
        }
    }
    __syncthreads();

    // ---- merge 4 quarters per token (ascending q, strict < => first-index) ----
    if (tid < 64) {
        float B1 = INF, B2 = INF; int CW = 0;
        #pragma unroll
        for (int qq = 0; qq < 4; ++qq) {
            const float pv = s_pv[qq][tid];
            const float p2 = s_p2[qq][tid];
            const int   pk = s_pk[qq][tid];
            if (pv < B1) { B2 = fminf(B1, p2); B1 = pv; CW = pk; }
            else         { B2 = fminf(B2, pv); }
        }
        s_idx[tid] = CW;
        if (B2 - B1 < EPS) atomicOr(&s_mask[tid >> 5], 1u << (tid & 31));
    }
    __syncthreads();

    // ---- exact fp32 rescan, COALESCED: lane = (row in 16-chunk, d-quarter) ----
    {
        int ui = 0;
        const int row = lane >> 2;       // 0..15
        const int c   = lane & 3;        // d-quarter
        for (int w = 0; w < 2; ++w) {
            unsigned m = s_mask[w];
            while (m) {
                const int bit = __ffs(m) - 1;
                m &= m - 1;
                const int tl = w * 32 + bit;
                if ((ui & 3) == q) {
                    // stage x (one 64-line gather), then lane's d-quarter from LDS
                    s_x[q][lane] = input[(size_t)b * DHW + (size_t)lane * HW + (hwb + tl)];
                    const float4* xs4 = (const float4*)&s_x[q][c * 16];
                    const float4 x0 = xs4[0], x1 = xs4[1], x2 = xs4[2], x3 = xs4[3];

                    float bestv = INF; int bestk = K;
                    #pragma unroll 4
                    for (int ch = 0; ch < 64; ++ch) {
                        const int k = ch * 16 + row;                  // ascending per lane
                        const float4* c4 = (const float4*)(codebook + (size_t)k * D + c * 16);
                        const float4 c0 = c4[0], c1 = c4[1], c2 = c4[2], c3 = c4[3];
                        float p0 = 0.f, p1 = 0.f, p2 = 0.f, p3 = 0.f;
                        p0 = fmaf(x0.x, c0.x, p0); p0 = fmaf(x0.y, c0.y, p0);
                        p0 = fmaf(x0.z, c0.z, p0); p0 = fmaf(x0.w, c0.w, p0);
                        p1 = fmaf(x1.x, c1.x, p1); p1 = fmaf(x1.y, c1.y, p1);
                        p1 = fmaf(x1.z, c1.z, p1); p1 = fmaf(x1.w, c1.w, p1);
                        p2 = fmaf(x2.x, c2.x, p2); p2 = fmaf(x2.y, c2.y, p2);
                        p2 = fmaf(x2.z, c2.z, p2); p2 = fmaf(x2.w, c2.w, p2);
                        p3 = fmaf(x3.x, c3.x, p3); p3 = fmaf(x3.y, c3.y, p3);
                        p3 = fmaf(x3.z, c3.z, p3); p3 = fmaf(x3.w, c3.w, p3);
                        float dp = (p0 + p1) + (p2 + p3);
                        dp += __shfl_xor(dp, 1, 64);                  // sum over quarters
                        dp += __shfl_xor(dp, 2, 64);
                        const float s = fmaf(-2.0f, dp, s_esq[k]);
                        if (s < bestv) { bestv = s; bestk = k; }
                    }
                    #pragma unroll
                    for (int off = 32; off >= 1; off >>= 1) {
                        const float ov = __shfl_xor(bestv, off, 64);
                        const int   ok = __shfl_xor(bestk, off, 64);
                        if (ov < bestv || (ov == bestv && ok < bestk)) { bestv = ov; bestk = ok; }
                    }
                    if (lane == 0) s_idx[tl] = bestk;
                }
                ++ui;
            }
        }
    }
    __syncthreads();

    // ---- epilogue: gather winner rows to LDS, then float4 stores ----
    {
        const int rs = tid >> 2;          // token slot 0..63
        const int c  = tid & 3;           // d-quarter
        const int idx = s_idx[rs];
        const float4* src = (const float4*)(codebook + (size_t)idx * D + c * 16);
        #pragma unroll
        for (int j = 0; j < 4; ++j) {
            const float4 v = src[j];
            float* dst = &s_q[rs][c * 16 + j * 4];
            dst[0] = v.x; dst[1] = v.y; dst[2] = v.z; dst[3] = v.w;
        }
    }
    __syncthreads();
    {
        float* ob = out + (size_t)b * DHW + hwb;
        #pragma unroll
        for (int pass = 0; pass < 4; ++pass) {
            const int d   = pass * 16 + (tid >> 4);
            const int hw4 = (tid & 15) * 4;
            float4 v;
            v.x = s_q[hw4 + 0][d];
            v.y = s_q[hw4 + 1][d];
            v.z = s_q[hw4 + 2][d];
            v.w = s_q[hw4 + 3][d];
            *(float4*)(ob + (size_t)d * HW + hw4) = v;
        }
        if (tid < 64) out[OUT_ELEMS + tok0 + tid] = (float)s_idx[tid];
    }
}

extern "C" void kernel_launch(void* const* d_in, const int* in_sizes, int n_in,
                              void* d_out, int out_size, void* d_ws, size_t ws_size,
                              hipStream_t stream) {
    const float* input    = (const float*)d_in[0];
    const float* codebook = (const float*)d_in[1];
    float* out            = (float*)d_out;

    _Float16* CH  = (_Float16*)d_ws;                   // 163840 B
    float*    esq = (float*)((char*)d_ws + 163840);    // 4096 B

    vq_prep<<<44, 256, 0, stream>>>(codebook, CH, esq);
    vq_scan<<<1024, 256, 0, stream>>>(input, codebook, CH, esq, out);
}

// Round 7
// 105.923 us; speedup vs baseline: 1.6428x; 1.2225x over previous
//
#include <hip/hip_runtime.h>

// VectorQuantizer R6: input (16,64,64,64) f32 channel-first, codebook (1024,64) f32.
// out = [quantized (16,64,64,64) f32 | indices (16,64,64) as f32].
//
// A = codebook, B = tokens, mfma_f32_32x32x16_f16, SPLIT-F16 3-pass:
//   v = v_hi + v_lo (f16 each); dot = hi*hi + hi*lo + lo*hi  (lo*lo ~2^-22 dropped)
//   -> score error ~3e-5. esq folded via hi/lo 5th-chunk vs ones-B (verified R3-R5).
// Tracking: value+slot in separate regs (no mantissa packing) -> exact gap test,
// EPS = 1e-3 -> ~1e-4 flag rate (~8 tokens chip-wide).
// Rescan: block-cooperative exact fp32 (64 rows x 4 quarters, coalesced),
// ascending-k strict-min tie-break; ties (gap 0) always flagged.

typedef _Float16 v8h  __attribute__((ext_vector_type(8)));
typedef float    v16f __attribute__((ext_vector_type(16)));

constexpr int   D         = 64;
constexpr int   K         = 1024;
constexpr int   HW        = 4096;
constexpr int   DHW       = D * HW;
constexpr int   OUT_ELEMS = 16 * DHW;
constexpr float EPS       = 1e-3f;

// CH: 32 tiles x 9 chunks x 64 lanes x 8 f16 = 288 KB.
// frag f = t*9+kc; CH[f*512 + lane*8 + j]:
//   kc 0-3: hi of -2*C[row = t*32+(lane&31)][k = kc*16+(lane>>5)*8+j]
//   kc 4-7: lo of same
//   kc 8  : lh==0: j0=e_hi, j1=e_lo (pairs with B5 = ones at k=0,1)

__global__ __launch_bounds__(256) void vq_prep(
    const float* __restrict__ cb, _Float16* __restrict__ CH, float* __restrict__ esq)
{
    const int blk = blockIdx.x, tid = threadIdx.x;
    if (blk < 72) {
        const int gid  = blk * 256 + tid;          // [0, 18432)
        const int lane = gid & 63;
        const int fid  = gid >> 6;                 // [0, 288)
        const int t    = fid / 9;
        const int kc   = fid - 9 * t;
        const int l31  = lane & 31;
        const int lh   = lane >> 5;
        const int cw   = t * 32 + l31;
        v8h h;
        if (kc < 8) {
            const int  kk = kc & 3;
            const bool lo = kc >= 4;
            const float* src = cb + cw * D + kk * 16 + lh * 8;
            #pragma unroll
            for (int j = 0; j < 8; ++j) {
                const float v = -2.0f * src[j];
                const _Float16 vh = (_Float16)v;
                h[j] = lo ? (_Float16)(v - (float)vh) : vh;
            }
        } else {
            #pragma unroll
            for (int j = 0; j < 8; ++j) h[j] = (_Float16)0.0f;
            if (lh == 0) {
                const float4* c4 = (const float4*)(cb + cw * D);
                float a0 = 0.f, a1 = 0.f, a2 = 0.f, a3 = 0.f;
                #pragma unroll
                for (int j = 0; j < 16; ++j) {
                    const float4 c = c4[j];
                    a0 = fmaf(c.x, c.x, a0);
                    a1 = fmaf(c.y, c.y, a1);
                    a2 = fmaf(c.z, c.z, a2);
                    a3 = fmaf(c.w, c.w, a3);
                }
                const float e = (a0 + a1) + (a2 + a3);
                const _Float16 ehi = (_Float16)e;
                h[0] = ehi;
                h[1] = (_Float16)(e - (float)ehi);
            }
        }
        *(v8h*)(CH + (size_t)fid * 512 + lane * 8) = h;
    } else {
        const int cw = (blk - 72) * 256 + tid;     // exact f32 e_sq for rescan
        const float4* c4 = (const float4*)(cb + cw * D);
        float a0 = 0.f, a1 = 0.f, a2 = 0.f, a3 = 0.f;
        #pragma unroll
        for (int j = 0; j < 16; ++j) {
            const float4 c = c4[j];
            a0 = fmaf(c.x, c.x, a0);
            a1 = fmaf(c.y, c.y, a1);
            a2 = fmaf(c.z, c.z, a2);
            a3 = fmaf(c.w, c.w, a3);
        }
        esq[cw] = (a0 + a1) + (a2 + a3);
    }
}

__global__ __launch_bounds__(256, 3) void vq_scan(
    const float* __restrict__ input,
    const float* __restrict__ codebook,
    const _Float16* __restrict__ CH,
    const float* __restrict__ esq,
    float* __restrict__ out)
{
    __shared__ _Float16 s_bf[2][2][4][64][8];  // [hi/lo][ct][kc][lane][8], 16 KB
    __shared__ float    s_esq[K];              // exact e_sq (rescan), 4 KB
    __shared__ float    s_pv[4][64];
    __shared__ float    s_p2[4][64];
    __shared__ int      s_pk[4][64];
    __shared__ int      s_idx[64];
    __shared__ int      s_list[64];
    __shared__ int      s_cnt;
    __shared__ float    s_xf[64];              // rescan token (f32)
    __shared__ float    s_redv[4];
    __shared__ int      s_redk[4];
    __shared__ float    s_q[64][65];           // winner rows for epilogue

    const int tid  = threadIdx.x;
    const int lane = tid & 63;
    const int q    = __builtin_amdgcn_readfirstlane(tid >> 6);  // K-quarter
    const int lh   = lane >> 5;
    const int tok0 = blockIdx.x * 64;
    const int b    = tok0 >> 12;
    const int hwb  = tok0 & 4095;

    if (tid == 0) s_cnt = 0;

    // ---- stage exact e_sq ----
    *(float4*)&s_esq[tid * 4] = *(const float4*)&esq[tid * 4];

    // ---- cooperative B staging: hi+lo split ----
    {
        const float* xb = input + (size_t)b * DHW + hwb;
        #pragma unroll
        for (int pass = 0; pass < 4; ++pass) {
            const int d   = pass * 16 + (tid >> 4);
            const int hw4 = (tid & 15) * 4;
            const float4 v = *(const float4*)(xb + (size_t)d * HW + hw4);
            const float vv[4] = {v.x, v.y, v.z, v.w};
            #pragma unroll
            for (int u = 0; u < 4; ++u) {
                const int tk = hw4 + u;
                const float f = vv[u];
                const _Float16 fh = (_Float16)f;
                s_bf[0][tk >> 5][d >> 4][((d >> 3) & 1) * 32 + (tk & 31)][d & 7] = fh;
                s_bf[1][tk >> 5][d >> 4][((d >> 3) & 1) * 32 + (tk & 31)][d & 7] =
                    (_Float16)(f - (float)fh);
            }
        }
    }
    __syncthreads();

    // ---- B fragments from LDS ----
    v8h bh[2][4], bl[2][4];
    #pragma unroll
    for (int ct = 0; ct < 2; ++ct)
        #pragma unroll
        for (int kc = 0; kc < 4; ++kc) {
            bh[ct][kc] = *(const v8h*)&s_bf[0][ct][kc][lane][0];
            bl[ct][kc] = *(const v8h*)&s_bf[1][ct][kc][lane][0];
        }

    // B5: ones at k=0,1 (pairs with esq chunk)
    v8h b5;
    #pragma unroll
    for (int j = 0; j < 8; ++j) b5[j] = (_Float16)0.0f;
    if (lh == 0) { b5[0] = (_Float16)1.0f; b5[1] = (_Float16)1.0f; }

    v16f Z = {0,0,0,0,0,0,0,0,0,0,0,0,0,0,0,0};
    const float INF = __builtin_huge_valf();
    float bv0 = INF, b20 = INF, bv1 = INF, b21 = INF;
    int   sl0 = 0, sl1 = 0;

    const v8h* Abase = (const v8h*)CH + lane;

    // ---- hot loop: 8 tiles x 26 MFMA (esq + 4kc x {hh, hl, lh}) ----
    #pragma unroll 2
    for (int t = 0; t < 8; ++t) {
        const v8h* Ap = Abase + (size_t)((q * 8 + t) * 9) * 64;
        const v8h ah0 = Ap[0],   ah1 = Ap[64],  ah2 = Ap[128], ah3 = Ap[192];
        const v8h al0 = Ap[256], al1 = Ap[320], al2 = Ap[384], al3 = Ap[448];
        const v8h ae  = Ap[512];

        v16f acc0 = __builtin_amdgcn_mfma_f32_32x32x16_f16(ae, b5, Z, 0, 0, 0);
        v16f acc1 = __builtin_amdgcn_mfma_f32_32x32x16_f16(ae, b5, Z, 0, 0, 0);

        acc0 = __builtin_amdgcn_mfma_f32_32x32x16_f16(ah0, bh[0][0], acc0, 0, 0, 0);
        acc1 = __builtin_amdgcn_mfma_f32_32x32x16_f16(ah0, bh[1][0], acc1, 0, 0, 0);
        acc0 = __builtin_amdgcn_mfma_f32_32x32x16_f16(ah1, bh[0][1], acc0, 0, 0, 0);
        acc1 = __builtin_amdgcn_mfma_f32_32x32x16_f16(ah1, bh[1][1], acc1, 0, 0, 0);
        acc0 = __builtin_amdgcn_mfma_f32_32x32x16_f16(ah2, bh[0][2], acc0, 0, 0, 0);
        acc1 = __builtin_amdgcn_mfma_f32_32x32x16_f16(ah2, bh[1][2], acc1, 0, 0, 0);
        acc0 = __builtin_amdgcn_mfma_f32_32x32x16_f16(ah3, bh[0][3], acc0, 0, 0, 0);
        acc1 = __builtin_amdgcn_mfma_f32_32x32x16_f16(ah3, bh[1][3], acc1, 0, 0, 0);

        acc0 = __builtin_amdgcn_mfma_f32_32x32x16_f16(ah0, bl[0][0], acc0, 0, 0, 0);
        acc1 = __builtin_amdgcn_mfma_f32_32x32x16_f16(ah0, bl[1][0], acc1, 0, 0, 0);
        acc0 = __builtin_amdgcn_mfma_f32_32x32x16_f16(ah1, bl[0][1], acc0, 0, 0, 0);
        acc1 = __builtin_amdgcn_mfma_f32_32x32x16_f16(ah1, bl[1][1], acc1, 0, 0, 0);
        acc0 = __builtin_amdgcn_mfma_f32_32x32x16_f16(ah2, bl[0][2], acc0, 0, 0, 0);
        acc1 = __builtin_amdgcn_mfma_f32_32x32x16_f16(ah2, bl[1][2], acc1, 0, 0, 0);
        acc0 = __builtin_amdgcn_mfma_f32_32x32x16_f16(ah3, bl[0][3], acc0, 0, 0, 0);
        acc1 = __builtin_amdgcn_mfma_f32_32x32x16_f16(ah3, bl[1][3], acc1, 0, 0, 0);

        acc0 = __builtin_amdgcn_mfma_f32_32x32x16_f16(al0, bh[0][0], acc0, 0, 0, 0);
        acc1 = __builtin_amdgcn_mfma_f32_32x32x16_f16(al0, bh[1][0], acc1, 0, 0, 0);
        acc0 = __builtin_amdgcn_mfma_f32_32x32x16_f16(al1, bh[0][1], acc0, 0, 0, 0);
        acc1 = __builtin_amdgcn_mfma_f32_32x32x16_f16(al1, bh[1][1], acc1, 0, 0, 0);
        acc0 = __builtin_amdgcn_mfma_f32_32x32x16_f16(al2, bh[0][2], acc0, 0, 0, 0);
        acc1 = __builtin_amdgcn_mfma_f32_32x32x16_f16(al2, bh[1][2], acc1, 0, 0, 0);
        acc0 = __builtin_amdgcn_mfma_f32_32x32x16_f16(al3, bh[0][3], acc0, 0, 0, 0);
        acc1 = __builtin_amdgcn_mfma_f32_32x32x16_f16(al3, bh[1][3], acc1, 0, 0, 0);

        // track top-2 value + slot (value & slot separate: exact gap test)
        #pragma unroll
        for (int r = 0; r < 16; ++r) {
            const int slot = (t << 4) | r;
            const float s0 = acc0[r];
            b20 = __builtin_amdgcn_fmed3f(s0, bv0, b20);
            if (s0 < bv0) { bv0 = s0; sl0 = slot; }
            const float s1 = acc1[r];
            b21 = __builtin_amdgcn_fmed3f(s1, bv1, b21);
            if (s1 < bv1) { bv1 = s1; sl1 = slot; }
        }
    }

    // ---- cross-half-row merge (lane <-> lane^32), decode cw ----
    #pragma unroll
    for (int ct = 0; ct < 2; ++ct) {
        const float bv = ct ? bv1 : bv0;
        const float b2 = ct ? b21 : b20;
        const int   sl = ct ? sl1 : sl0;
        const float obv = __shfl_xor(bv, 32, 64);
        const float ob2 = __shfl_xor(b2, 32, 64);
        const int   osl = __shfl_xor(sl, 32, 64);
        const bool  oth = obv < bv;            // strict: ties keep own; exact ties flagged
        const float B1  = oth ? obv : bv;
        const float B2  = fminf(fmaxf(bv, obv), fminf(b2, ob2));
        const int   wsl = oth ? osl : sl;
        const int   wlh = oth ? (lh ^ 1) : lh;
        const int   r   = wsl & 15;
        const int   tt  = wsl >> 4;
        const int   cw  = (q * 8 + tt) * 32 + (r & 3) + 8 * (r >> 2) + 4 * wlh;
        if (lane < 32) {
            s_pv[q][ct * 32 + lane] = B1;
            s_p2[q][ct * 32 + lane] = B2;
            s_pk[q][ct * 32 + lane] = cw;
        }
    }
    __syncthreads();

    // ---- merge 4 quarters per token; flag near-ties into list ----
    if (tid < 64) {
        float B1 = INF, B2 = INF; int CW = 0;
        #pragma unroll
        for (int qq = 0; qq < 4; ++qq) {
            const float pv = s_pv[qq][tid];
            const float p2 = s_p2[qq][tid];
            const int   pk = s_pk[qq][tid];
            if (pv < B1) { B2 = fminf(B1, p2); B1 = pv; CW = pk; }
            else         { B2 = fminf(B2, pv); }
        }
        s_idx[tid] = CW;
        if (B2 - B1 < EPS) {
            const int p = atomicAdd(&s_cnt, 1);
            s_list[p] = tid;
        }
    }
    __syncthreads();

    // ---- exact fp32 rescan, BLOCK-cooperative (rare: ~1e-4 of tokens) ----
    {
        const int cnt = s_cnt;
        const int rr  = tid >> 2;   // codeword row within 64-chunk
        const int c   = tid & 3;    // d-quarter
        for (int ii = 0; ii < cnt; ++ii) {
            const int tl = s_list[ii];
            if (tid < 64) s_xf[tid] = input[(size_t)b * DHW + (size_t)tid * HW + (hwb + tl)];
            __syncthreads();
            const float4* xs4 = (const float4*)&s_xf[c * 16];
            const float4 x0 = xs4[0], x1 = xs4[1], x2 = xs4[2], x3 = xs4[3];
            float bestv = INF; int bestk = K;
            #pragma unroll 4
            for (int i = 0; i < 16; ++i) {
                const int k = i * 64 + rr;                     // ascending per thread
                const float4* c4 = (const float4*)(codebook + (size_t)k * D + c * 16);
                const float4 c0 = c4[0], c1 = c4[1], c2 = c4[2], c3 = c4[3];
                float p0 = 0.f, p1 = 0.f, p2 = 0.f, p3 = 0.f;
                p0 = fmaf(x0.x, c0.x, p0); p0 = fmaf(x0.y, c0.y, p0);
                p0 = fmaf(x0.z, c0.z, p0); p0 = fmaf(x0.w, c0.w, p0);
                p1 = fmaf(x1.x, c1.x, p1); p1 = fmaf(x1.y, c1.y, p1);
                p1 = fmaf(x1.z, c1.z, p1); p1 = fmaf(x1.w, c1.w, p1);
                p2 = fmaf(x2.x, c2.x, p2); p2 = fmaf(x2.y, c2.y, p2);
                p2 = fmaf(x2.z, c2.z, p2); p2 = fmaf(x2.w, c2.w, p2);
                p3 = fmaf(x3.x, c3.x, p3); p3 = fmaf(x3.y, c3.y, p3);
                p3 = fmaf(x3.z, c3.z, p3); p3 = fmaf(x3.w, c3.w, p3);
                float dp = (p0 + p1) + (p2 + p3);
                dp += __shfl_xor(dp, 1, 64);                   // sum over d-quarters
                dp += __shfl_xor(dp, 2, 64);
                const float s = fmaf(-2.0f, dp, s_esq[k]);
                if (s < bestv) { bestv = s; bestk = k; }
            }
            #pragma unroll
            for (int off = 4; off <= 32; off <<= 1) {          // reduce over rows in wave
                const float ov = __shfl_xor(bestv, off, 64);
                const int   ok = __shfl_xor(bestk, off, 64);
                if (ov < bestv || (ov == bestv && ok < bestk)) { bestv = ov; bestk = ok; }
            }
            if (lane == 0) { s_redv[q] = bestv; s_redk[q] = bestk; }
            __syncthreads();
            if (tid == 0) {
                float bb = s_redv[0]; int bk = s_redk[0];
                #pragma unroll
                for (int w = 1; w < 4; ++w) {
                    const float v = s_redv[w]; const int kk = s_redk[w];
                    if (v < bb || (v == bb && kk < bk)) { bb = v; bk = kk; }
                }
                s_idx[tl] = bk;
            }
            __syncthreads();
        }
    }

    // ---- epilogue: gather winner rows to LDS, then float4 stores ----
    {
        const int rs  = tid >> 2;
        const int c   = tid & 3;
        const int idx = s_idx[rs];
        const float4* src = (const float4*)(codebook + (size_t)idx * D + c * 16);
        #pragma unroll
        for (int j = 0; j < 4; ++j) {
            const float4 v = src[j];
            float* dst = &s_q[rs][c * 16 + j * 4];
            dst[0] = v.x; dst[1] = v.y; dst[2] = v.z; dst[3] = v.w;
        }
    }
    __syncthreads();
    {
        float* ob = out + (size_t)b * DHW + hwb;
        #pragma unroll
        for (int pass = 0; pass < 4; ++pass) {
            const int d   = pass * 16 + (tid >> 4);
            const int hw4 = (tid & 15) * 4;
            float4 v;
            v.x = s_q[hw4 + 0][d];
            v.y = s_q[hw4 + 1][d];
            v.z = s_q[hw4 + 2][d];
            v.w = s_q[hw4 + 3][d];
            *(float4*)(ob + (size_t)d * HW + hw4) = v;
        }
        if (tid < 64) out[OUT_ELEMS + tok0 + tid] = (float)s_idx[tid];
    }
}

extern "C" void kernel_launch(void* const* d_in, const int* in_sizes, int n_in,
                              void* d_out, int out_size, void* d_ws, size_t ws_size,
                              hipStream_t stream) {
    const float* input    = (const float*)d_in[0];
    const float* codebook = (const float*)d_in[1];
    float* out            = (float*)d_out;

    _Float16* CH  = (_Float16*)d_ws;                   // 294912 B
    float*    esq = (float*)((char*)d_ws + 294912);    // 4096 B

    vq_prep<<<76, 256, 0, stream>>>(codebook, CH, esq);
    vq_scan<<<1024, 256, 0, stream>>>(input, codebook, CH, esq, out);
}